// Round 1
// baseline (1737.663 us; speedup 1.0000x reference)
//
#include <hip/hip_runtime.h>
#include <stdint.h>

#define T_STEPS 8
#define N_NODES 100000
#define E_EDGES 3200000
#define NB1 250
#define CHUNK 400          // NB1*CHUNK == N_NODES
#define NCAND (NB1*16)     // 4000

// ---- sortable key: value desc, tie -> lower index ----
__device__ __forceinline__ unsigned long long make_key(float v, int idx) {
    uint32_t u = __float_as_uint(v);
    u = (u & 0x80000000u) ? ~u : (u | 0x80000000u);
    return (((unsigned long long)u) << 32) | (unsigned long long)(~(uint32_t)idx);
}
__device__ __forceinline__ float key_val(unsigned long long k) {
    uint32_t u = (uint32_t)(k >> 32);
    u = (u & 0x80000000u) ? (u & 0x7FFFFFFFu) : ~u;
    return __uint_as_float(u);
}
__device__ __forceinline__ int key_idx(unsigned long long k) {
    return (int)(~(uint32_t)(k & 0xFFFFFFFFu));
}

__device__ __forceinline__ unsigned long long shfl_xor_u64(unsigned long long x, int mask) {
    uint32_t lo = (uint32_t)x, hi = (uint32_t)(x >> 32);
    lo = __shfl_xor((unsigned int)lo, mask);
    hi = __shfl_xor((unsigned int)hi, mask);
    return (((unsigned long long)hi) << 32) | lo;
}

__device__ __forceinline__ void wave_argmax(unsigned long long& m, int& mp) {
    #pragma unroll
    for (int off = 32; off; off >>= 1) {
        unsigned long long o = shfl_xor_u64(m, off);
        int op = __shfl_xor(mp, off);
        if (o > m) { m = o; mp = op; }
    }
}

__device__ __forceinline__ float dot16(const float4* __restrict__ xr, const float* w) {
    float4 a = xr[0], b = xr[1], c = xr[2], d = xr[3];
    return a.x*w[0] + a.y*w[1] + a.z*w[2] + a.w*w[3]
         + b.x*w[4] + b.y*w[5] + b.z*w[6] + b.w*w[7]
         + c.x*w[8] + c.y*w[9] + c.z*w[10] + c.w*w[11]
         + d.x*w[12] + d.y*w[13] + d.z*w[14] + d.w*w[15];
}

// K1: y = (X_t @ p)/||p||, per-block top-16 candidates (sorted desc)
__global__ __launch_bounds__(256) void k_y_topk(const float* __restrict__ Xt,
                                                const float* __restrict__ p,
                                                unsigned long long* __restrict__ cand) {
    __shared__ unsigned long long keys[CHUNK];
    __shared__ unsigned long long wm[4];
    __shared__ int wp[4];
    int tid = threadIdx.x;
    float pv[16];
    #pragma unroll
    for (int i = 0; i < 16; i++) pv[i] = p[i];
    float pn = 0.f;
    #pragma unroll
    for (int i = 0; i < 16; i++) pn += pv[i] * pv[i];
    float inv = 1.0f / sqrtf(pn);
    int base = blockIdx.x * CHUNK;
    for (int i = tid; i < CHUNK; i += 256) {
        int n = base + i;
        float y = dot16((const float4*)(Xt + (size_t)n * 16), pv) * inv;
        keys[i] = make_key(y, n);
    }
    __syncthreads();
    for (int k = 0; k < 16; k++) {
        unsigned long long m = 0ULL; int mp = -1;
        for (int i = tid; i < CHUNK; i += 256) {
            unsigned long long v = keys[i];
            if (v > m) { m = v; mp = i; }
        }
        wave_argmax(m, mp);
        if ((tid & 63) == 0) { wm[tid >> 6] = m; wp[tid >> 6] = mp; }
        __syncthreads();
        if (tid == 0) {
            unsigned long long best = wm[0]; int bp = wp[0];
            #pragma unroll
            for (int w2 = 1; w2 < 4; w2++) if (wm[w2] > best) { best = wm[w2]; bp = wp[w2]; }
            cand[blockIdx.x * 16 + k] = best;
            keys[bp] = 0ULL;
        }
        __syncthreads();
    }
}

// K2: single block — global top-16 merge, GRU update on W, w_eff = W_new @ lin_w
__global__ __launch_bounds__(256) void k_topk_gru(
    const unsigned long long* __restrict__ cand,
    const float* __restrict__ Xt,
    const float* __restrict__ Wp_g,
    const float* __restrict__ W_Z, const float* __restrict__ U_Z, const float* __restrict__ B_Z,
    const float* __restrict__ W_R, const float* __restrict__ U_R, const float* __restrict__ B_R,
    const float* __restrict__ W_H, const float* __restrict__ U_H, const float* __restrict__ B_H,
    const float* __restrict__ lin_w,
    float* __restrict__ W_out, float* __restrict__ weff) {
    __shared__ unsigned long long keys[NCAND];
    __shared__ unsigned long long wm[4];
    __shared__ int wp[4];
    __shared__ int sidx[16];
    __shared__ float sval[16];
    __shared__ float Xs[16][16];
    __shared__ float Wp[16][16];
    __shared__ float RgW[16][16];
    __shared__ float Wn[16][16];
    int tid = threadIdx.x;
    for (int i = tid; i < NCAND; i += 256) keys[i] = cand[i];
    __syncthreads();
    for (int k = 0; k < 16; k++) {
        unsigned long long m = 0ULL; int mp = -1;
        for (int i = tid; i < NCAND; i += 256) {
            unsigned long long v = keys[i];
            if (v > m) { m = v; mp = i; }
        }
        wave_argmax(m, mp);
        if ((tid & 63) == 0) { wm[tid >> 6] = m; wp[tid >> 6] = mp; }
        __syncthreads();
        if (tid == 0) {
            unsigned long long best = wm[0]; int bp = wp[0];
            #pragma unroll
            for (int w2 = 1; w2 < 4; w2++) if (wm[w2] > best) { best = wm[w2]; bp = wp[w2]; }
            sidx[k] = key_idx(best);
            sval[k] = key_val(best);
            keys[bp] = 0ULL;
        }
        __syncthreads();
    }
    // Xs[f][k] = X_t[idx[k], f] * yk[k] ; Wp[i][j] = W_prev
    {
        int k = tid >> 4, f = tid & 15;
        Xs[f][k] = Xt[(size_t)sidx[k] * 16 + f] * sval[k];
        Wp[k][f] = Wp_g[k * 16 + f];
    }
    __syncthreads();
    int i = tid >> 4, j = tid & 15;
    float az = 0.f, ar = 0.f, uz = 0.f, ur = 0.f;
    #pragma unroll
    for (int m = 0; m < 16; m++) {
        az += W_Z[i * 16 + m] * Xs[m][j];
        ar += W_R[i * 16 + m] * Xs[m][j];
        uz += U_Z[i * 16 + m] * Wp[m][j];
        ur += U_R[i * 16 + m] * Wp[m][j];
    }
    float Zg = 1.0f / (1.0f + expf(-(az + uz + B_Z[i * 16 + j])));
    float Rg = 1.0f / (1.0f + expf(-(ar + ur + B_R[i * 16 + j])));
    RgW[i][j] = Rg * Wp[i][j];
    __syncthreads();
    float ah = 0.f, uh = 0.f;
    #pragma unroll
    for (int m = 0; m < 16; m++) {
        ah += W_H[i * 16 + m] * Xs[m][j];
        uh += U_H[i * 16 + m] * RgW[m][j];
    }
    float Ht = tanhf(ah + uh + B_H[i * 16 + j]);
    float wnew = (1.0f - Zg) * Wp[i][j] + Zg * Ht;
    Wn[i][j] = wnew;
    W_out[i * 16 + j] = wnew;
    __syncthreads();
    if (tid < 16) {
        float acc = 0.f;
        #pragma unroll
        for (int jj = 0; jj < 16; jj++) acc += Wn[tid][jj] * lin_w[jj];
        weff[tid] = acc;
    }
}

// K3: s[n] = X_t[n,:] . w_eff ; out[t,n] = lin_b
__global__ __launch_bounds__(256) void k_s_init(const float* __restrict__ Xt,
                                                const float* __restrict__ weff,
                                                const float* __restrict__ lin_b,
                                                float* __restrict__ s,
                                                float* __restrict__ out_t) {
    __shared__ float w[16];
    __shared__ float lb;
    if (threadIdx.x < 16) w[threadIdx.x] = weff[threadIdx.x];
    if (threadIdx.x == 0) lb = lin_b[0];
    __syncthreads();
    int n = blockIdx.x * 256 + threadIdx.x;
    if (n < N_NODES) {
        float v = dot16((const float4*)(Xt + (size_t)n * 16), w);
        s[n] = v;
        out_t[n] = lb;
    }
}

// K4: out[t, row_e] += val_e * s[col_e]  (4 edges/thread)
__global__ __launch_bounds__(256) void k_scatter(const int4* __restrict__ row4,
                                                 const int4* __restrict__ col4,
                                                 const float4* __restrict__ val4,
                                                 const float* __restrict__ s,
                                                 float* __restrict__ out_t) {
    int i = blockIdx.x * 256 + threadIdx.x;
    int4 r = row4[i];
    int4 c = col4[i];
    float4 v = val4[i];
    atomicAdd(&out_t[r.x], v.x * s[c.x]);
    atomicAdd(&out_t[r.y], v.y * s[c.y]);
    atomicAdd(&out_t[r.z], v.z * s[c.z]);
    atomicAdd(&out_t[r.w], v.w * s[c.w]);
}

extern "C" void kernel_launch(void* const* d_in, const int* in_sizes, int n_in,
                              void* d_out, int out_size, void* d_ws, size_t ws_size,
                              hipStream_t stream) {
    const float* X     = (const float*)d_in[0];
    const int*   erow  = (const int*)d_in[1];
    const int*   ecol  = (const int*)d_in[2];
    const float* evalv = (const float*)d_in[3];
    const float* p     = (const float*)d_in[4];
    const float* W_Z   = (const float*)d_in[5];
    const float* U_Z   = (const float*)d_in[6];
    const float* B_Z   = (const float*)d_in[7];
    const float* W_R   = (const float*)d_in[8];
    const float* U_R   = (const float*)d_in[9];
    const float* B_R   = (const float*)d_in[10];
    const float* W_H   = (const float*)d_in[11];
    const float* U_H   = (const float*)d_in[12];
    const float* B_H   = (const float*)d_in[13];
    const float* Winit = (const float*)d_in[14];
    const float* lin_w = (const float*)d_in[15];
    const float* lin_b = (const float*)d_in[16];
    float* out = (float*)d_out;

    char* ws = (char*)d_ws;
    unsigned long long* cand = (unsigned long long*)ws;        // NCAND*8 = 32000 B
    float* Wst  = (float*)(ws + 32768);                        // 256 f
    float* weff = (float*)(ws + 32768 + 1024);                 // 16 f
    float* s    = (float*)(ws + 32768 + 2048);                 // N f

    for (int t = 0; t < T_STEPS; t++) {
        const float* Xt = X + (size_t)t * N_NODES * 16;
        float* out_t = out + (size_t)t * N_NODES;
        k_y_topk<<<NB1, 256, 0, stream>>>(Xt, p, cand);
        const float* Wprev = (t == 0) ? Winit : Wst;
        k_topk_gru<<<1, 256, 0, stream>>>(cand, Xt, Wprev,
                                          W_Z, U_Z, B_Z, W_R, U_R, B_R, W_H, U_H, B_H,
                                          lin_w, Wst, weff);
        k_s_init<<<(N_NODES + 255) / 256, 256, 0, stream>>>(Xt, weff, lin_b, s, out_t);
        k_scatter<<<E_EDGES / 4 / 256, 256, 0, stream>>>((const int4*)(erow + (size_t)t * E_EDGES),
                                                         (const int4*)(ecol + (size_t)t * E_EDGES),
                                                         (const float4*)(evalv + (size_t)t * E_EDGES),
                                                         s, out_t);
    }
}

// Round 2
// 1332.959 us; speedup vs baseline: 1.3036x; 1.3036x over previous
//
#include <hip/hip_runtime.h>
#include <stdint.h>

#define T_STEPS 8
#define N_NODES 100000
#define E_EDGES 3200000
#define NB1 250
#define CHUNK 400          // NB1*CHUNK == N_NODES
#define NB3 391            // ceil(N/256)
#define NCAND_T 4000       // NB1*16 per t

// ---- sortable key: value desc, tie -> lower index ----
__device__ __forceinline__ unsigned long long make_key(float v, int idx) {
    uint32_t u = __float_as_uint(v);
    u = (u & 0x80000000u) ? ~u : (u | 0x80000000u);
    return (((unsigned long long)u) << 32) | (unsigned long long)(~(uint32_t)idx);
}
__device__ __forceinline__ float key_val(unsigned long long k) {
    uint32_t u = (uint32_t)(k >> 32);
    u = (u & 0x80000000u) ? (u & 0x7FFFFFFFu) : ~u;
    return __uint_as_float(u);
}
__device__ __forceinline__ int key_idx(unsigned long long k) {
    return (int)(~(uint32_t)(k & 0xFFFFFFFFu));
}

__device__ __forceinline__ unsigned long long shfl_xor_u64(unsigned long long x, int mask) {
    uint32_t lo = (uint32_t)x, hi = (uint32_t)(x >> 32);
    lo = __shfl_xor((unsigned int)lo, mask);
    hi = __shfl_xor((unsigned int)hi, mask);
    return (((unsigned long long)hi) << 32) | lo;
}

__device__ __forceinline__ void wave_argmax(unsigned long long& m, int& mp) {
    #pragma unroll
    for (int off = 32; off; off >>= 1) {
        unsigned long long o = shfl_xor_u64(m, off);
        int op = __shfl_xor(mp, off);
        if (o > m) { m = o; mp = op; }
    }
}

__device__ __forceinline__ uint32_t get_xcc() {
    uint32_t x;
    asm volatile("s_getreg_b32 %0, hwreg(HW_REG_XCC_ID)" : "=s"(x));
    return x & 7u;
}

__device__ __forceinline__ float dot16(const float4* __restrict__ xr, const float* w) {
    float4 a = xr[0], b = xr[1], c = xr[2], d = xr[3];
    return a.x*w[0] + a.y*w[1] + a.z*w[2] + a.w*w[3]
         + b.x*w[4] + b.y*w[5] + b.z*w[6] + b.w*w[7]
         + c.x*w[8] + c.y*w[9] + c.z*w[10] + c.w*w[11]
         + d.x*w[12] + d.y*w[13] + d.z*w[14] + d.w*w[15];
}

// K1: for all t — y = (X_t @ p)/||p||, per-block top-16 candidates (sorted desc).
// Also zeroes the rep buffer (tier A).
__global__ __launch_bounds__(256) void k_y_topk_all(const float* __restrict__ X,
                                                    const float* __restrict__ p,
                                                    unsigned long long* __restrict__ cand,
                                                    float* __restrict__ rep, int do_zero) {
    __shared__ unsigned long long keys[CHUNK];
    __shared__ unsigned long long wm[4];
    __shared__ int wp[4];
    int tid = threadIdx.x;
    if (do_zero) {  // 2000 blocks x 3200 floats == 8*8*N
        float* z = rep + (size_t)blockIdx.x * 3200;
        for (int i = tid; i < 3200; i += 256) z[i] = 0.f;
    }
    int t = blockIdx.x / NB1;
    int b = blockIdx.x % NB1;
    const float* Xt = X + (size_t)t * N_NODES * 16;
    float pv[16];
    #pragma unroll
    for (int i = 0; i < 16; i++) pv[i] = p[i];
    float pn = 0.f;
    #pragma unroll
    for (int i = 0; i < 16; i++) pn += pv[i] * pv[i];
    float inv = 1.0f / sqrtf(pn);
    int base = b * CHUNK;
    for (int i = tid; i < CHUNK; i += 256) {
        int n = base + i;
        float y = dot16((const float4*)(Xt + (size_t)n * 16), pv) * inv;
        keys[i] = make_key(y, n);
    }
    __syncthreads();
    for (int k = 0; k < 16; k++) {
        unsigned long long m = 0ULL; int mp = -1;
        for (int i = tid; i < CHUNK; i += 256) {
            unsigned long long v = keys[i];
            if (v > m) { m = v; mp = i; }
        }
        wave_argmax(m, mp);
        if ((tid & 63) == 0) { wm[tid >> 6] = m; wp[tid >> 6] = mp; }
        __syncthreads();
        if (tid == 0) {
            unsigned long long best = wm[0]; int bp = wp[0];
            #pragma unroll
            for (int w2 = 1; w2 < 4; w2++) if (wm[w2] > best) { best = wm[w2]; bp = wp[w2]; }
            cand[(size_t)t * NCAND_T + b * 16 + k] = best;
            keys[bp] = 0ULL;
        }
        __syncthreads();
    }
}

// K2: one block, 512 threads = 8 waves. Wave w merges t=w's 250 sorted lists
// (k-way merge, heads in registers, no syncthreads). Then sequential GRU chain.
__global__ __launch_bounds__(512) void k_merge_gru(
    const unsigned long long* __restrict__ cand,   // [8][4000]
    const float* __restrict__ X,                   // [8][N][16]
    const float* __restrict__ Winit,
    const float* __restrict__ W_Z, const float* __restrict__ U_Z, const float* __restrict__ B_Z,
    const float* __restrict__ W_R, const float* __restrict__ U_R, const float* __restrict__ B_R,
    const float* __restrict__ W_H, const float* __restrict__ U_H, const float* __restrict__ B_H,
    const float* __restrict__ lin_w,
    float* __restrict__ weff_g) {                  // [8][16]
    __shared__ float mWZ[256], mUZ[256], mBZ[256], mWR[256], mUR[256], mBR[256];
    __shared__ float mWH[256], mUH[256], mBH[256], mLW[16];
    __shared__ int   sidx[8][16];
    __shared__ float sval[8][16];
    __shared__ float Xs[16][16];
    __shared__ float Wcur[16][16];
    __shared__ float RgW[16][16];
    int tid = threadIdx.x;
    if (tid < 256) {
        mWZ[tid] = W_Z[tid]; mUZ[tid] = U_Z[tid]; mBZ[tid] = B_Z[tid];
        mWR[tid] = W_R[tid]; mUR[tid] = U_R[tid]; mBR[tid] = B_R[tid];
        mWH[tid] = W_H[tid]; mUH[tid] = U_H[tid]; mBH[tid] = B_H[tid];
        Wcur[tid >> 4][tid & 15] = Winit[tid];
        if (tid < 16) mLW[tid] = lin_w[tid];
    }
    // ---- per-wave k-way merge: wave w handles t=w ----
    {
        int w = tid >> 6, lane = tid & 63;
        const unsigned long long* ct = cand + (size_t)w * NCAND_T;
        int cb = lane * 4;
        unsigned long long h0 = 0, h1 = 0, h2 = 0, h3 = 0;
        int p0 = 0, p1 = 0, p2 = 0, p3 = 0;
        if (cb + 0 < NB1) h0 = ct[(cb + 0) * 16];
        if (cb + 1 < NB1) h1 = ct[(cb + 1) * 16];
        if (cb + 2 < NB1) h2 = ct[(cb + 2) * 16];
        if (cb + 3 < NB1) h3 = ct[(cb + 3) * 16];
        for (int k = 0; k < 16; k++) {
            unsigned long long m = h0; int pay = (lane << 2) | 0;
            if (h1 > m) { m = h1; pay = (lane << 2) | 1; }
            if (h2 > m) { m = h2; pay = (lane << 2) | 2; }
            if (h3 > m) { m = h3; pay = (lane << 2) | 3; }
            wave_argmax(m, pay);
            if (lane == 0) { sidx[w][k] = key_idx(m); sval[w][k] = key_val(m); }
            if ((pay >> 2) == lane) {
                switch (pay & 3) {
                case 0: p0++; h0 = (p0 < 16) ? ct[(cb + 0) * 16 + p0] : 0ULL; break;
                case 1: p1++; h1 = (p1 < 16) ? ct[(cb + 1) * 16 + p1] : 0ULL; break;
                case 2: p2++; h2 = (p2 < 16) ? ct[(cb + 2) * 16 + p2] : 0ULL; break;
                default: p3++; h3 = (p3 < 16) ? ct[(cb + 3) * 16 + p3] : 0ULL; break;
                }
            }
        }
    }
    __syncthreads();
    // ---- sequential GRU chain over t ----
    int i = (tid & 255) >> 4, j = tid & 15;
    for (int t = 0; t < T_STEPS; t++) {
        if (tid < 256) {
            int k = tid >> 4, f = tid & 15;
            Xs[f][k] = X[(size_t)t * N_NODES * 16 + (size_t)sidx[t][k] * 16 + f] * sval[t][k];
        }
        __syncthreads();
        float Zg = 0.f, wn = 0.f;
        if (tid < 256) {
            float az = 0.f, ar = 0.f, uz = 0.f, ur = 0.f;
            #pragma unroll
            for (int m = 0; m < 16; m++) {
                az += mWZ[i * 16 + m] * Xs[m][j];
                ar += mWR[i * 16 + m] * Xs[m][j];
                uz += mUZ[i * 16 + m] * Wcur[m][j];
                ur += mUR[i * 16 + m] * Wcur[m][j];
            }
            Zg = 1.0f / (1.0f + expf(-(az + uz + mBZ[i * 16 + j])));
            float Rg = 1.0f / (1.0f + expf(-(ar + ur + mBR[i * 16 + j])));
            RgW[i][j] = Rg * Wcur[i][j];
        }
        __syncthreads();
        if (tid < 256) {
            float ah = 0.f, uh = 0.f;
            #pragma unroll
            for (int m = 0; m < 16; m++) {
                ah += mWH[i * 16 + m] * Xs[m][j];
                uh += mUH[i * 16 + m] * RgW[m][j];
            }
            float Ht = tanhf(ah + uh + mBH[i * 16 + j]);
            wn = (1.0f - Zg) * Wcur[i][j] + Zg * Ht;
        }
        __syncthreads();
        if (tid < 256) Wcur[i][j] = wn;
        __syncthreads();
        if (tid < 16) {
            float acc = 0.f;
            #pragma unroll
            for (int jj = 0; jj < 16; jj++) acc += Wcur[tid][jj] * mLW[jj];
            weff_g[t * 16 + tid] = acc;
        }
        __syncthreads();
    }
}

// K3: s[t][n] = X_t[n,:] . w_eff[t]  (all t); optionally init out with lin_b (tier B)
__global__ __launch_bounds__(256) void k_s_all(const float* __restrict__ X,
                                               const float* __restrict__ weff,
                                               float* __restrict__ s,
                                               float* __restrict__ out,
                                               const float* __restrict__ lin_b,
                                               int init_out) {
    int t = blockIdx.x / NB3;
    int b = blockIdx.x % NB3;
    __shared__ float w[16];
    if (threadIdx.x < 16) w[threadIdx.x] = weff[t * 16 + threadIdx.x];
    __syncthreads();
    int n = b * 256 + threadIdx.x;
    if (n < N_NODES) {
        float v = dot16((const float4*)(X + ((size_t)t * N_NODES + n) * 16), w);
        s[(size_t)t * N_NODES + n] = v;
        if (init_out) out[(size_t)t * N_NODES + n] = lin_b[0];
    }
}

// K4a (tier A): scatter into per-XCD replicas with L2-local (workgroup-scope) atomics
__global__ __launch_bounds__(256) void k_scatter_rep(const int* __restrict__ erow,
                                                     const int* __restrict__ ecol,
                                                     const float* __restrict__ evalv,
                                                     const float* __restrict__ s,
                                                     float* __restrict__ rep) {
    int t = blockIdx.x & 7;        // round-robin dispatch -> each XCD mostly one t
    int b = blockIdx.x >> 3;
    uint32_t xcc = get_xcc();
    float* r = rep + ((size_t)xcc * T_STEPS + t) * N_NODES;
    const float* st = s + (size_t)t * N_NODES;
    size_t eb = (size_t)t * E_EDGES;
    int i = b * 256 + threadIdx.x;
    int4 rr = ((const int4*)(erow + eb))[i];
    int4 cc = ((const int4*)(ecol + eb))[i];
    float4 vv = ((const float4*)(evalv + eb))[i];
    __hip_atomic_fetch_add(&r[rr.x], vv.x * st[cc.x], __ATOMIC_RELAXED, __HIP_MEMORY_SCOPE_WORKGROUP);
    __hip_atomic_fetch_add(&r[rr.y], vv.y * st[cc.y], __ATOMIC_RELAXED, __HIP_MEMORY_SCOPE_WORKGROUP);
    __hip_atomic_fetch_add(&r[rr.z], vv.z * st[cc.z], __ATOMIC_RELAXED, __HIP_MEMORY_SCOPE_WORKGROUP);
    __hip_atomic_fetch_add(&r[rr.w], vv.w * st[cc.w], __ATOMIC_RELAXED, __HIP_MEMORY_SCOPE_WORKGROUP);
}

// K4b (tier B fallback): device-scope atomics straight into out
__global__ __launch_bounds__(256) void k_scatter_dev(const int* __restrict__ erow,
                                                     const int* __restrict__ ecol,
                                                     const float* __restrict__ evalv,
                                                     const float* __restrict__ s,
                                                     float* __restrict__ out) {
    int t = blockIdx.x & 7;
    int b = blockIdx.x >> 3;
    float* o = out + (size_t)t * N_NODES;
    const float* st = s + (size_t)t * N_NODES;
    size_t eb = (size_t)t * E_EDGES;
    int i = b * 256 + threadIdx.x;
    int4 rr = ((const int4*)(erow + eb))[i];
    int4 cc = ((const int4*)(ecol + eb))[i];
    float4 vv = ((const float4*)(evalv + eb))[i];
    atomicAdd(&o[rr.x], vv.x * st[cc.x]);
    atomicAdd(&o[rr.y], vv.y * st[cc.y]);
    atomicAdd(&o[rr.z], vv.z * st[cc.z]);
    atomicAdd(&o[rr.w], vv.w * st[cc.w]);
}

// K5 (tier A): out[t][n] = lin_b + sum_x rep[x][t][n]
__global__ __launch_bounds__(256) void k_reduce(const float* __restrict__ rep,
                                                const float* __restrict__ lin_b,
                                                float* __restrict__ out) {
    int t = blockIdx.x / NB3;
    int b = blockIdx.x % NB3;
    int n = b * 256 + threadIdx.x;
    if (n >= N_NODES) return;
    float acc = lin_b[0];
    #pragma unroll
    for (int x = 0; x < 8; x++) acc += rep[((size_t)x * T_STEPS + t) * N_NODES + n];
    out[(size_t)t * N_NODES + n] = acc;
}

extern "C" void kernel_launch(void* const* d_in, const int* in_sizes, int n_in,
                              void* d_out, int out_size, void* d_ws, size_t ws_size,
                              hipStream_t stream) {
    const float* X     = (const float*)d_in[0];
    const int*   erow  = (const int*)d_in[1];
    const int*   ecol  = (const int*)d_in[2];
    const float* evalv = (const float*)d_in[3];
    const float* p     = (const float*)d_in[4];
    const float* W_Z   = (const float*)d_in[5];
    const float* U_Z   = (const float*)d_in[6];
    const float* B_Z   = (const float*)d_in[7];
    const float* W_R   = (const float*)d_in[8];
    const float* U_R   = (const float*)d_in[9];
    const float* B_R   = (const float*)d_in[10];
    const float* W_H   = (const float*)d_in[11];
    const float* U_H   = (const float*)d_in[12];
    const float* B_H   = (const float*)d_in[13];
    const float* Winit = (const float*)d_in[14];
    const float* lin_w = (const float*)d_in[15];
    const float* lin_b = (const float*)d_in[16];
    float* out = (float*)d_out;

    char* ws = (char*)d_ws;
    const size_t CAND_OFF = 0;                     // 8*4000*8 = 256000 B
    const size_t WEFF_OFF = 262144;                // 512 B
    const size_t S_OFF    = 266240;                // 8*N*4 = 3,200,000 B
    const size_t REP_OFF  = 3473408;               // 8*8*N*4 = 25,600,000 B
    unsigned long long* cand = (unsigned long long*)(ws + CAND_OFF);
    float* weff = (float*)(ws + WEFF_OFF);
    float* s    = (float*)(ws + S_OFF);
    float* rep  = (float*)(ws + REP_OFF);
    const size_t NEED_A = REP_OFF + (size_t)8 * T_STEPS * N_NODES * 4;
    const bool tierA = (ws_size >= NEED_A);

    k_y_topk_all<<<T_STEPS * NB1, 256, 0, stream>>>(X, p, cand, rep, tierA ? 1 : 0);
    k_merge_gru<<<1, 512, 0, stream>>>(cand, X, Winit,
                                       W_Z, U_Z, B_Z, W_R, U_R, B_R, W_H, U_H, B_H,
                                       lin_w, weff);
    k_s_all<<<T_STEPS * NB3, 256, 0, stream>>>(X, weff, s, out, lin_b, tierA ? 0 : 1);
    const int SC_BLKS = T_STEPS * (E_EDGES / 4 / 256);  // 25000
    if (tierA) {
        k_scatter_rep<<<SC_BLKS, 256, 0, stream>>>(erow, ecol, evalv, s, rep);
        k_reduce<<<T_STEPS * NB3, 256, 0, stream>>>(rep, lin_b, out);
    } else {
        k_scatter_dev<<<SC_BLKS, 256, 0, stream>>>(erow, ecol, evalv, s, out);
    }
}

// Round 3
// 277.440 us; speedup vs baseline: 6.2632x; 4.8045x over previous
//
#include <hip/hip_runtime.h>
#include <hip/hip_bf16.h>
#include <stdint.h>

#define T_STEPS 8
#define N_NODES 100000
#define E_EDGES 3200000
#define NB1 250
#define CHUNK 400          // NB1*CHUNK == N_NODES
#define NB3 391            // ceil(N/256)
#define NCAND_T 4000       // NB1*16 per t
#define NSLICE 8
#define ESLICE (E_EDGES / NSLICE)   // 400000

// ---- sortable key: value desc, tie -> lower index ----
__device__ __forceinline__ unsigned long long make_key(float v, int idx) {
    uint32_t u = __float_as_uint(v);
    u = (u & 0x80000000u) ? ~u : (u | 0x80000000u);
    return (((unsigned long long)u) << 32) | (unsigned long long)(~(uint32_t)idx);
}
__device__ __forceinline__ float key_val(unsigned long long k) {
    uint32_t u = (uint32_t)(k >> 32);
    u = (u & 0x80000000u) ? (u & 0x7FFFFFFFu) : ~u;
    return __uint_as_float(u);
}
__device__ __forceinline__ int key_idx(unsigned long long k) {
    return (int)(~(uint32_t)(k & 0xFFFFFFFFu));
}

__device__ __forceinline__ unsigned long long shfl_xor_u64(unsigned long long x, int mask) {
    uint32_t lo = (uint32_t)x, hi = (uint32_t)(x >> 32);
    lo = __shfl_xor((unsigned int)lo, mask);
    hi = __shfl_xor((unsigned int)hi, mask);
    return (((unsigned long long)hi) << 32) | lo;
}

__device__ __forceinline__ void wave_argmax(unsigned long long& m, int& mp) {
    #pragma unroll
    for (int off = 32; off; off >>= 1) {
        unsigned long long o = shfl_xor_u64(m, off);
        int op = __shfl_xor(mp, off);
        if (o > m) { m = o; mp = op; }
    }
}

__device__ __forceinline__ float dot16(const float4* __restrict__ xr, const float* w) {
    float4 a = xr[0], b = xr[1], c = xr[2], d = xr[3];
    return a.x*w[0] + a.y*w[1] + a.z*w[2] + a.w*w[3]
         + b.x*w[4] + b.y*w[5] + b.z*w[6] + b.w*w[7]
         + c.x*w[8] + c.y*w[9] + c.z*w[10] + c.w*w[11]
         + d.x*w[12] + d.y*w[13] + d.z*w[14] + d.w*w[15];
}

// K1: for all t — y = (X_t @ p)/||p||, per-block top-16 candidates (sorted desc).
__global__ __launch_bounds__(256) void k_y_topk_all(const float* __restrict__ X,
                                                    const float* __restrict__ p,
                                                    unsigned long long* __restrict__ cand) {
    __shared__ unsigned long long keys[CHUNK];
    __shared__ unsigned long long wm[4];
    __shared__ int wp[4];
    int tid = threadIdx.x;
    int t = blockIdx.x / NB1;
    int b = blockIdx.x % NB1;
    const float* Xt = X + (size_t)t * N_NODES * 16;
    float pv[16];
    #pragma unroll
    for (int i = 0; i < 16; i++) pv[i] = p[i];
    float pn = 0.f;
    #pragma unroll
    for (int i = 0; i < 16; i++) pn += pv[i] * pv[i];
    float inv = 1.0f / sqrtf(pn);
    int base = b * CHUNK;
    for (int i = tid; i < CHUNK; i += 256) {
        int n = base + i;
        float y = dot16((const float4*)(Xt + (size_t)n * 16), pv) * inv;
        keys[i] = make_key(y, n);
    }
    __syncthreads();
    for (int k = 0; k < 16; k++) {
        unsigned long long m = 0ULL; int mp = -1;
        for (int i = tid; i < CHUNK; i += 256) {
            unsigned long long v = keys[i];
            if (v > m) { m = v; mp = i; }
        }
        wave_argmax(m, mp);
        if ((tid & 63) == 0) { wm[tid >> 6] = m; wp[tid >> 6] = mp; }
        __syncthreads();
        if (tid == 0) {
            unsigned long long best = wm[0]; int bp = wp[0];
            #pragma unroll
            for (int w2 = 1; w2 < 4; w2++) if (wm[w2] > best) { best = wm[w2]; bp = wp[w2]; }
            cand[(size_t)t * NCAND_T + b * 16 + k] = best;
            keys[bp] = 0ULL;
        }
        __syncthreads();
    }
}

// K2: one block, 512 threads = 8 waves. Wave w merges t=w's 250 sorted lists
// (k-way merge, heads in registers). Then sequential GRU chain.
__global__ __launch_bounds__(512) void k_merge_gru(
    const unsigned long long* __restrict__ cand,   // [8][4000]
    const float* __restrict__ X,                   // [8][N][16]
    const float* __restrict__ Winit,
    const float* __restrict__ W_Z, const float* __restrict__ U_Z, const float* __restrict__ B_Z,
    const float* __restrict__ W_R, const float* __restrict__ U_R, const float* __restrict__ B_R,
    const float* __restrict__ W_H, const float* __restrict__ U_H, const float* __restrict__ B_H,
    const float* __restrict__ lin_w,
    float* __restrict__ weff_g) {                  // [8][16]
    __shared__ float mWZ[256], mUZ[256], mBZ[256], mWR[256], mUR[256], mBR[256];
    __shared__ float mWH[256], mUH[256], mBH[256], mLW[16];
    __shared__ int   sidx[8][16];
    __shared__ float sval[8][16];
    __shared__ float Xs[16][16];
    __shared__ float Wcur[16][16];
    __shared__ float RgW[16][16];
    int tid = threadIdx.x;
    if (tid < 256) {
        mWZ[tid] = W_Z[tid]; mUZ[tid] = U_Z[tid]; mBZ[tid] = B_Z[tid];
        mWR[tid] = W_R[tid]; mUR[tid] = U_R[tid]; mBR[tid] = B_R[tid];
        mWH[tid] = W_H[tid]; mUH[tid] = U_H[tid]; mBH[tid] = B_H[tid];
        Wcur[tid >> 4][tid & 15] = Winit[tid];
        if (tid < 16) mLW[tid] = lin_w[tid];
    }
    {
        int w = tid >> 6, lane = tid & 63;
        const unsigned long long* ct = cand + (size_t)w * NCAND_T;
        int cb = lane * 4;
        unsigned long long h0 = 0, h1 = 0, h2 = 0, h3 = 0;
        int p0 = 0, p1 = 0, p2 = 0, p3 = 0;
        if (cb + 0 < NB1) h0 = ct[(cb + 0) * 16];
        if (cb + 1 < NB1) h1 = ct[(cb + 1) * 16];
        if (cb + 2 < NB1) h2 = ct[(cb + 2) * 16];
        if (cb + 3 < NB1) h3 = ct[(cb + 3) * 16];
        for (int k = 0; k < 16; k++) {
            unsigned long long m = h0; int pay = (lane << 2) | 0;
            if (h1 > m) { m = h1; pay = (lane << 2) | 1; }
            if (h2 > m) { m = h2; pay = (lane << 2) | 2; }
            if (h3 > m) { m = h3; pay = (lane << 2) | 3; }
            wave_argmax(m, pay);
            if (lane == 0) { sidx[w][k] = key_idx(m); sval[w][k] = key_val(m); }
            if ((pay >> 2) == lane) {
                switch (pay & 3) {
                case 0: p0++; h0 = (p0 < 16) ? ct[(cb + 0) * 16 + p0] : 0ULL; break;
                case 1: p1++; h1 = (p1 < 16) ? ct[(cb + 1) * 16 + p1] : 0ULL; break;
                case 2: p2++; h2 = (p2 < 16) ? ct[(cb + 2) * 16 + p2] : 0ULL; break;
                default: p3++; h3 = (p3 < 16) ? ct[(cb + 3) * 16 + p3] : 0ULL; break;
                }
            }
        }
    }
    __syncthreads();
    int i = (tid & 255) >> 4, j = tid & 15;
    for (int t = 0; t < T_STEPS; t++) {
        if (tid < 256) {
            int k = tid >> 4, f = tid & 15;
            Xs[f][k] = X[(size_t)t * N_NODES * 16 + (size_t)sidx[t][k] * 16 + f] * sval[t][k];
        }
        __syncthreads();
        float Zg = 0.f, wn = 0.f;
        if (tid < 256) {
            float az = 0.f, ar = 0.f, uz = 0.f, ur = 0.f;
            #pragma unroll
            for (int m = 0; m < 16; m++) {
                az += mWZ[i * 16 + m] * Xs[m][j];
                ar += mWR[i * 16 + m] * Xs[m][j];
                uz += mUZ[i * 16 + m] * Wcur[m][j];
                ur += mUR[i * 16 + m] * Wcur[m][j];
            }
            Zg = 1.0f / (1.0f + expf(-(az + uz + mBZ[i * 16 + j])));
            float Rg = 1.0f / (1.0f + expf(-(ar + ur + mBR[i * 16 + j])));
            RgW[i][j] = Rg * Wcur[i][j];
        }
        __syncthreads();
        if (tid < 256) {
            float ah = 0.f, uh = 0.f;
            #pragma unroll
            for (int m = 0; m < 16; m++) {
                ah += mWH[i * 16 + m] * Xs[m][j];
                uh += mUH[i * 16 + m] * RgW[m][j];
            }
            float Ht = tanhf(ah + uh + mBH[i * 16 + j]);
            wn = (1.0f - Zg) * Wcur[i][j] + Zg * Ht;
        }
        __syncthreads();
        if (tid < 256) Wcur[i][j] = wn;
        __syncthreads();
        if (tid < 16) {
            float acc = 0.f;
            #pragma unroll
            for (int jj = 0; jj < 16; jj++) acc += Wcur[tid][jj] * mLW[jj];
            weff_g[t * 16 + tid] = acc;
        }
        __syncthreads();
    }
}

// K3: s[t][n] = X_t[n,:] . w_eff[t]
__global__ __launch_bounds__(256) void k_s_all(const float* __restrict__ X,
                                               const float* __restrict__ weff,
                                               float* __restrict__ s) {
    int t = blockIdx.x / NB3;
    int b = blockIdx.x % NB3;
    __shared__ float w[16];
    if (threadIdx.x < 16) w[threadIdx.x] = weff[t * 16 + threadIdx.x];
    __syncthreads();
    int n = b * 256 + threadIdx.x;
    if (n < N_NODES) {
        float v = dot16((const float4*)(X + ((size_t)t * N_NODES + n) * 16), w);
        s[(size_t)t * N_NODES + n] = v;
    }
}

// K4: LDS range-accumulate scatter — ZERO global atomics.
// Block = (t = bid&7 [one t per XCD], m = bid>>3 -> slice = m/nrng, r = m%nrng).
// LDS acc covers rows [r*rng, r*rng+rng); scan slice edges, ds_add in-range,
// flush bf16 to rep[bid][rng].
extern "C" __global__ __launch_bounds__(1024) void k_scatter_lds(
    const int* __restrict__ erow, const int* __restrict__ ecol,
    const float* __restrict__ evalv, const float* __restrict__ s,
    __hip_bfloat16* __restrict__ rep, int rng, int nrng) {
    extern __shared__ float acc[];
    int bid = blockIdx.x;
    int t = bid & 7;
    int m = bid >> 3;
    int slice = m / nrng;
    int r = m - slice * nrng;
    int base = r * rng;
    int lim = min(rng, N_NODES - base);
    int tid = threadIdx.x;
    int bd = blockDim.x;
    for (int i = tid; i < lim; i += bd) acc[i] = 0.f;
    __syncthreads();
    const float* st = s + (size_t)t * N_NODES;
    size_t eb = (size_t)t * E_EDGES + (size_t)slice * ESLICE;
    const int4* r4 = (const int4*)(erow + eb);
    const int4* c4 = (const int4*)(ecol + eb);
    const float4* v4 = (const float4*)(evalv + eb);
    const int n4 = ESLICE / 4;
    for (int i = tid; i < n4; i += bd) {
        int4 rr = r4[i];
        int4 cc = c4[i];
        float4 vv = v4[i];
        int l0 = rr.x - base, l1 = rr.y - base, l2 = rr.z - base, l3 = rr.w - base;
        if ((unsigned)l0 < (unsigned)lim) atomicAdd(&acc[l0], vv.x * st[cc.x]);
        if ((unsigned)l1 < (unsigned)lim) atomicAdd(&acc[l1], vv.y * st[cc.y]);
        if ((unsigned)l2 < (unsigned)lim) atomicAdd(&acc[l2], vv.z * st[cc.z]);
        if ((unsigned)l3 < (unsigned)lim) atomicAdd(&acc[l3], vv.w * st[cc.w]);
    }
    __syncthreads();
    __hip_bfloat16* rp = rep + (size_t)bid * rng;
    for (int i = tid; i < lim; i += bd) rp[i] = __float2bfloat16(acc[i]);
}

// K5: out[t][n] = lin_b + sum_slices rep
__global__ __launch_bounds__(256) void k_reduce(const __hip_bfloat16* __restrict__ rep,
                                                const float* __restrict__ lin_b,
                                                float* __restrict__ out,
                                                int rng, int nrng) {
    int t = blockIdx.x / NB3;
    int b = blockIdx.x % NB3;
    int n = b * 256 + threadIdx.x;
    if (n >= N_NODES) return;
    int r = n / rng;
    int local = n - r * rng;
    float acc = lin_b[0];
    #pragma unroll
    for (int sl = 0; sl < NSLICE; sl++) {
        int bid = t + 8 * (sl * nrng + r);
        acc += __bfloat162float(rep[(size_t)bid * rng + local]);
    }
    out[(size_t)t * N_NODES + n] = acc;
}

extern "C" void kernel_launch(void* const* d_in, const int* in_sizes, int n_in,
                              void* d_out, int out_size, void* d_ws, size_t ws_size,
                              hipStream_t stream) {
    const float* X     = (const float*)d_in[0];
    const int*   erow  = (const int*)d_in[1];
    const int*   ecol  = (const int*)d_in[2];
    const float* evalv = (const float*)d_in[3];
    const float* p     = (const float*)d_in[4];
    const float* W_Z   = (const float*)d_in[5];
    const float* U_Z   = (const float*)d_in[6];
    const float* B_Z   = (const float*)d_in[7];
    const float* W_R   = (const float*)d_in[8];
    const float* U_R   = (const float*)d_in[9];
    const float* B_R   = (const float*)d_in[10];
    const float* W_H   = (const float*)d_in[11];
    const float* U_H   = (const float*)d_in[12];
    const float* B_H   = (const float*)d_in[13];
    const float* Winit = (const float*)d_in[14];
    const float* lin_w = (const float*)d_in[15];
    const float* lin_b = (const float*)d_in[16];
    float* out = (float*)d_out;

    // Preferred config: 4 ranges x 32768 = 128 KB LDS (1 block/CU), 256 blocks.
    // Fallback (if >64KB LDS attr fails): 7 x 14336 = 56 KB LDS, 448 blocks.
    int rng = 32768, nrng = 4;
    size_t dynLDS = (size_t)rng * sizeof(float);
    if (hipFuncSetAttribute((const void*)k_scatter_lds,
                            hipFuncAttributeMaxDynamicSharedMemorySize,
                            (int)dynLDS) != hipSuccess) {
        rng = 14336; nrng = 7;
        dynLDS = (size_t)rng * sizeof(float);
    }
    const int SC_BLKS = T_STEPS * nrng * NSLICE;

    char* ws = (char*)d_ws;
    float* s    = (float*)ws;                           // 3,200,000 B
    float* weff = (float*)(ws + 3200000);               // 512 B
    unsigned long long* cand = (unsigned long long*)(ws + 3201024); // 256,000 B
    __hip_bfloat16* rep = (__hip_bfloat16*)(ws + 3457024);
    // rep max: 448 * 14336 * 2 = 12.8 MB or 256 * 32768 * 2 = 16.8 MB -> total <= 20.3 MB

    k_y_topk_all<<<T_STEPS * NB1, 256, 0, stream>>>(X, p, cand);
    k_merge_gru<<<1, 512, 0, stream>>>(cand, X, Winit,
                                       W_Z, U_Z, B_Z, W_R, U_R, B_R, W_H, U_H, B_H,
                                       lin_w, weff);
    k_s_all<<<T_STEPS * NB3, 256, 0, stream>>>(X, weff, s);
    k_scatter_lds<<<SC_BLKS, 1024, dynLDS, stream>>>(erow, ecol, evalv, s, rep, rng, nrng);
    k_reduce<<<T_STEPS * NB3, 256, 0, stream>>>(rep, lin_b, out, rng, nrng);
}

// Round 4
// 265.092 us; speedup vs baseline: 6.5549x; 1.0466x over previous
//
#include <hip/hip_runtime.h>
#include <stdint.h>

#define T_STEPS 8
#define N_NODES 100000
#define E_EDGES 3200000
#define NB1 250
#define CHUNK 400          // NB1*CHUNK == N_NODES
#define NB3 391            // ceil(N/256)
#define NCAND_T 4000       // NB1*16 per t
#define NSLICE 8
#define ESLICE (E_EDGES / NSLICE)   // 400000
#define RNG_BITS 15
#define RNG (1 << RNG_BITS)         // 32768 -> 128 KB LDS
#define NRNG 4                      // ceil(100000/32768)
#define SC_BLKS (T_STEPS * NRNG * NSLICE)  // 256 = 1 block/CU

// ---- bf16 pack/unpack (RNE) ----
__device__ __forceinline__ uint16_t f2bf(float x) {
    uint32_t b = __float_as_uint(x);
    b += 0x7FFFu + ((b >> 16) & 1u);
    return (uint16_t)(b >> 16);
}
__device__ __forceinline__ float bf2f(uint16_t u) {
    return __uint_as_float(((uint32_t)u) << 16);
}

// ---- sortable key: value desc, tie -> lower index ----
__device__ __forceinline__ unsigned long long make_key(float v, int idx) {
    uint32_t u = __float_as_uint(v);
    u = (u & 0x80000000u) ? ~u : (u | 0x80000000u);
    return (((unsigned long long)u) << 32) | (unsigned long long)(~(uint32_t)idx);
}
__device__ __forceinline__ float key_val(unsigned long long k) {
    uint32_t u = (uint32_t)(k >> 32);
    u = (u & 0x80000000u) ? (u & 0x7FFFFFFFu) : ~u;
    return __uint_as_float(u);
}
__device__ __forceinline__ int key_idx(unsigned long long k) {
    return (int)(~(uint32_t)(k & 0xFFFFFFFFu));
}

__device__ __forceinline__ unsigned long long shfl_xor_u64(unsigned long long x, int mask) {
    uint32_t lo = (uint32_t)x, hi = (uint32_t)(x >> 32);
    lo = __shfl_xor((unsigned int)lo, mask);
    hi = __shfl_xor((unsigned int)hi, mask);
    return (((unsigned long long)hi) << 32) | lo;
}

__device__ __forceinline__ void wave_argmax(unsigned long long& m, int& mp) {
    #pragma unroll
    for (int off = 32; off; off >>= 1) {
        unsigned long long o = shfl_xor_u64(m, off);
        int op = __shfl_xor(mp, off);
        if (o > m) { m = o; mp = op; }
    }
}

__device__ __forceinline__ float dot16(const float4* __restrict__ xr, const float* w) {
    float4 a = xr[0], b = xr[1], c = xr[2], d = xr[3];
    return a.x*w[0] + a.y*w[1] + a.z*w[2] + a.w*w[3]
         + b.x*w[4] + b.y*w[5] + b.z*w[6] + b.w*w[7]
         + c.x*w[8] + c.y*w[9] + c.z*w[10] + c.w*w[11]
         + d.x*w[12] + d.y*w[13] + d.z*w[14] + d.w*w[15];
}

// K1: for all t — y = (X_t @ p)/||p||, per-block top-16 candidates (sorted desc).
__global__ __launch_bounds__(256) void k_y_topk_all(const float* __restrict__ X,
                                                    const float* __restrict__ p,
                                                    unsigned long long* __restrict__ cand) {
    __shared__ unsigned long long keys[CHUNK];
    __shared__ unsigned long long wm[4];
    __shared__ int wp[4];
    int tid = threadIdx.x;
    int t = blockIdx.x / NB1;
    int b = blockIdx.x % NB1;
    const float* Xt = X + (size_t)t * N_NODES * 16;
    float pv[16];
    #pragma unroll
    for (int i = 0; i < 16; i++) pv[i] = p[i];
    float pn = 0.f;
    #pragma unroll
    for (int i = 0; i < 16; i++) pn += pv[i] * pv[i];
    float inv = 1.0f / sqrtf(pn);
    int base = b * CHUNK;
    for (int i = tid; i < CHUNK; i += 256) {
        int n = base + i;
        float y = dot16((const float4*)(Xt + (size_t)n * 16), pv) * inv;
        keys[i] = make_key(y, n);
    }
    __syncthreads();
    for (int k = 0; k < 16; k++) {
        unsigned long long m = 0ULL; int mp = -1;
        for (int i = tid; i < CHUNK; i += 256) {
            unsigned long long v = keys[i];
            if (v > m) { m = v; mp = i; }
        }
        wave_argmax(m, mp);
        if ((tid & 63) == 0) { wm[tid >> 6] = m; wp[tid >> 6] = mp; }
        __syncthreads();
        if (tid == 0) {
            unsigned long long best = wm[0]; int bp = wp[0];
            #pragma unroll
            for (int w2 = 1; w2 < 4; w2++) if (wm[w2] > best) { best = wm[w2]; bp = wp[w2]; }
            cand[(size_t)t * NCAND_T + b * 16 + k] = best;
            keys[bp] = 0ULL;
        }
        __syncthreads();
    }
}

// K2: one block, 512 threads = 8 waves. Wave w merges t=w's 250 sorted lists
// (k-way merge, heads in registers). Then batch-prefetch all Xs, then GRU chain.
__global__ __launch_bounds__(512) void k_merge_gru(
    const unsigned long long* __restrict__ cand,   // [8][4000]
    const float* __restrict__ X,                   // [8][N][16]
    const float* __restrict__ Winit,
    const float* __restrict__ W_Z, const float* __restrict__ U_Z, const float* __restrict__ B_Z,
    const float* __restrict__ W_R, const float* __restrict__ U_R, const float* __restrict__ B_R,
    const float* __restrict__ W_H, const float* __restrict__ U_H, const float* __restrict__ B_H,
    const float* __restrict__ lin_w,
    float* __restrict__ weff_g) {                  // [8][16]
    __shared__ float mWZ[256], mUZ[256], mBZ[256], mWR[256], mUR[256], mBR[256];
    __shared__ float mWH[256], mUH[256], mBH[256], mLW[16];
    __shared__ int   sidx[8][16];
    __shared__ float sval[8][16];
    __shared__ float Xs_all[8][16][16];   // [t][f][k]
    __shared__ float Wcur[16][16];
    __shared__ float RgW[16][16];
    int tid = threadIdx.x;
    if (tid < 256) {
        mWZ[tid] = W_Z[tid]; mUZ[tid] = U_Z[tid]; mBZ[tid] = B_Z[tid];
        mWR[tid] = W_R[tid]; mUR[tid] = U_R[tid]; mBR[tid] = B_R[tid];
        mWH[tid] = W_H[tid]; mUH[tid] = U_H[tid]; mBH[tid] = B_H[tid];
        Wcur[tid >> 4][tid & 15] = Winit[tid];
        if (tid < 16) mLW[tid] = lin_w[tid];
    }
    {
        int w = tid >> 6, lane = tid & 63;
        const unsigned long long* ct = cand + (size_t)w * NCAND_T;
        int cb = lane * 4;
        unsigned long long h0 = 0, h1 = 0, h2 = 0, h3 = 0;
        int p0 = 0, p1 = 0, p2 = 0, p3 = 0;
        if (cb + 0 < NB1) h0 = ct[(cb + 0) * 16];
        if (cb + 1 < NB1) h1 = ct[(cb + 1) * 16];
        if (cb + 2 < NB1) h2 = ct[(cb + 2) * 16];
        if (cb + 3 < NB1) h3 = ct[(cb + 3) * 16];
        for (int k = 0; k < 16; k++) {
            unsigned long long m = h0; int pay = (lane << 2) | 0;
            if (h1 > m) { m = h1; pay = (lane << 2) | 1; }
            if (h2 > m) { m = h2; pay = (lane << 2) | 2; }
            if (h3 > m) { m = h3; pay = (lane << 2) | 3; }
            wave_argmax(m, pay);
            if (lane == 0) { sidx[w][k] = key_idx(m); sval[w][k] = key_val(m); }
            if ((pay >> 2) == lane) {
                switch (pay & 3) {
                case 0: p0++; h0 = (p0 < 16) ? ct[(cb + 0) * 16 + p0] : 0ULL; break;
                case 1: p1++; h1 = (p1 < 16) ? ct[(cb + 1) * 16 + p1] : 0ULL; break;
                case 2: p2++; h2 = (p2 < 16) ? ct[(cb + 2) * 16 + p2] : 0ULL; break;
                default: p3++; h3 = (p3 < 16) ? ct[(cb + 3) * 16 + p3] : 0ULL; break;
                }
            }
        }
    }
    __syncthreads();
    // batched Xs prefetch for ALL t: 2048 scattered loads in flight at once
    for (int e = tid; e < 8 * 256; e += 512) {
        int tt = e >> 8, kk = (e >> 4) & 15, ff = e & 15;
        Xs_all[tt][ff][kk] = X[(size_t)tt * N_NODES * 16 + (size_t)sidx[tt][kk] * 16 + ff]
                           * sval[tt][kk];
    }
    __syncthreads();
    int i = (tid & 255) >> 4, j = tid & 15;
    for (int t = 0; t < T_STEPS; t++) {
        float Zg = 0.f, wn = 0.f;
        if (tid < 256) {
            float az = 0.f, ar = 0.f, uz = 0.f, ur = 0.f;
            #pragma unroll
            for (int m = 0; m < 16; m++) {
                az += mWZ[i * 16 + m] * Xs_all[t][m][j];
                ar += mWR[i * 16 + m] * Xs_all[t][m][j];
                uz += mUZ[i * 16 + m] * Wcur[m][j];
                ur += mUR[i * 16 + m] * Wcur[m][j];
            }
            Zg = 1.0f / (1.0f + expf(-(az + uz + mBZ[i * 16 + j])));
            float Rg = 1.0f / (1.0f + expf(-(ar + ur + mBR[i * 16 + j])));
            RgW[i][j] = Rg * Wcur[i][j];
        }
        __syncthreads();
        if (tid < 256) {
            float ah = 0.f, uh = 0.f;
            #pragma unroll
            for (int m = 0; m < 16; m++) {
                ah += mWH[i * 16 + m] * Xs_all[t][m][j];
                uh += mUH[i * 16 + m] * RgW[m][j];
            }
            float Ht = tanhf(ah + uh + mBH[i * 16 + j]);
            wn = (1.0f - Zg) * Wcur[i][j] + Zg * Ht;
        }
        __syncthreads();
        if (tid < 256) Wcur[i][j] = wn;
        __syncthreads();
        if (tid < 16) {
            float acc = 0.f;
            #pragma unroll
            for (int jj = 0; jj < 16; jj++) acc += Wcur[tid][jj] * mLW[jj];
            weff_g[t * 16 + tid] = acc;
        }
        __syncthreads();
    }
}

// K3: s[t][n] = X_t[n,:] . w_eff[t]
__global__ __launch_bounds__(256) void k_s_all(const float* __restrict__ X,
                                               const float* __restrict__ weff,
                                               float* __restrict__ s) {
    int t = blockIdx.x / NB3;
    int b = blockIdx.x % NB3;
    __shared__ float w[16];
    if (threadIdx.x < 16) w[threadIdx.x] = weff[t * 16 + threadIdx.x];
    __syncthreads();
    int n = b * 256 + threadIdx.x;
    if (n < N_NODES) {
        float v = dot16((const float4*)(X + ((size_t)t * N_NODES + n) * 16), w);
        s[(size_t)t * N_NODES + n] = v;
    }
}

// K4: LDS range-accumulate scatter, unroll x4 (16 edges in flight per thread).
#define PKT(Rr, Cc, Vv) do {                                                   \
    int l0 = Rr.x - base, l1 = Rr.y - base, l2 = Rr.z - base, l3 = Rr.w - base;\
    bool b0 = (unsigned)l0 < (unsigned)RNG, b1 = (unsigned)l1 < (unsigned)RNG, \
         b2 = (unsigned)l2 < (unsigned)RNG, b3 = (unsigned)l3 < (unsigned)RNG; \
    float g0 = b0 ? st[Cc.x] : 0.f, g1 = b1 ? st[Cc.y] : 0.f,                  \
          g2 = b2 ? st[Cc.z] : 0.f, g3 = b3 ? st[Cc.w] : 0.f;                  \
    if (b0) atomicAdd(&acc[l0], Vv.x * g0);                                    \
    if (b1) atomicAdd(&acc[l1], Vv.y * g1);                                    \
    if (b2) atomicAdd(&acc[l2], Vv.z * g2);                                    \
    if (b3) atomicAdd(&acc[l3], Vv.w * g3);                                    \
} while (0)

extern "C" __global__ __launch_bounds__(1024) void k_scatter_lds(
    const int* __restrict__ erow, const int* __restrict__ ecol,
    const float* __restrict__ evalv, const float* __restrict__ s,
    uint16_t* __restrict__ rep) {
    extern __shared__ float acc[];
    const int bid = blockIdx.x;
    const int t = bid & 7;          // one t per XCD (round-robin dispatch)
    const int m = bid >> 3;
    const int slice = m >> 2;       // 0..7
    const int r = m & 3;            // 0..3
    const int base = r << RNG_BITS;
    const int tid = threadIdx.x;
    float4* a4 = (float4*)acc;
    #pragma unroll
    for (int q = 0; q < RNG / 4 / 1024; q++)
        a4[tid + q * 1024] = make_float4(0.f, 0.f, 0.f, 0.f);
    __syncthreads();
    const float* __restrict__ st = s + (size_t)t * N_NODES;
    const size_t eb = (size_t)t * E_EDGES + (size_t)slice * ESLICE;
    const int4* __restrict__ r4 = (const int4*)(erow + eb);
    const int4* __restrict__ c4 = (const int4*)(ecol + eb);
    const float4* __restrict__ v4 = (const float4*)(evalv + eb);
    const int n4 = ESLICE / 4;      // 100000

    int i = tid;
    for (; i + 3 * 1024 < n4; i += 4 * 1024) {
        int4 R0 = r4[i], R1 = r4[i + 1024], R2 = r4[i + 2048], R3 = r4[i + 3072];
        int4 C0 = c4[i], C1 = c4[i + 1024], C2 = c4[i + 2048], C3 = c4[i + 3072];
        float4 V0 = v4[i], V1 = v4[i + 1024], V2 = v4[i + 2048], V3 = v4[i + 3072];
        PKT(R0, C0, V0);
        PKT(R1, C1, V1);
        PKT(R2, C2, V2);
        PKT(R3, C3, V3);
    }
    for (; i < n4; i += 1024) {
        int4 R0 = r4[i]; int4 C0 = c4[i]; float4 V0 = v4[i];
        PKT(R0, C0, V0);
    }
    __syncthreads();
    ushort4* rp4 = (ushort4*)(rep + (size_t)bid * RNG);
    #pragma unroll
    for (int q = 0; q < RNG / 4 / 1024; q++) {
        float4 a = a4[tid + q * 1024];
        ushort4 u;
        u.x = f2bf(a.x); u.y = f2bf(a.y); u.z = f2bf(a.z); u.w = f2bf(a.w);
        rp4[tid + q * 1024] = u;
    }
}

// K5: out[t][n] = lin_b + sum_slices rep
__global__ __launch_bounds__(256) void k_reduce(const uint16_t* __restrict__ rep,
                                                const float* __restrict__ lin_b,
                                                float* __restrict__ out) {
    int t = blockIdx.x / NB3;
    int b = blockIdx.x % NB3;
    int n = b * 256 + threadIdx.x;
    if (n >= N_NODES) return;
    int r = n >> RNG_BITS;
    int local = n & (RNG - 1);
    float acc = lin_b[0];
    #pragma unroll
    for (int sl = 0; sl < NSLICE; sl++) {
        int bid = t + 8 * (sl * NRNG + r);
        acc += bf2f(rep[(size_t)bid * RNG + local]);
    }
    out[(size_t)t * N_NODES + n] = acc;
}

extern "C" void kernel_launch(void* const* d_in, const int* in_sizes, int n_in,
                              void* d_out, int out_size, void* d_ws, size_t ws_size,
                              hipStream_t stream) {
    const float* X     = (const float*)d_in[0];
    const int*   erow  = (const int*)d_in[1];
    const int*   ecol  = (const int*)d_in[2];
    const float* evalv = (const float*)d_in[3];
    const float* p     = (const float*)d_in[4];
    const float* W_Z   = (const float*)d_in[5];
    const float* U_Z   = (const float*)d_in[6];
    const float* B_Z   = (const float*)d_in[7];
    const float* W_R   = (const float*)d_in[8];
    const float* U_R   = (const float*)d_in[9];
    const float* B_R   = (const float*)d_in[10];
    const float* W_H   = (const float*)d_in[11];
    const float* U_H   = (const float*)d_in[12];
    const float* B_H   = (const float*)d_in[13];
    const float* Winit = (const float*)d_in[14];
    const float* lin_w = (const float*)d_in[15];
    const float* lin_b = (const float*)d_in[16];
    float* out = (float*)d_out;

    size_t dynLDS = (size_t)RNG * sizeof(float);   // 128 KB (worked in R3)
    (void)hipFuncSetAttribute((const void*)k_scatter_lds,
                              hipFuncAttributeMaxDynamicSharedMemorySize,
                              (int)dynLDS);

    char* ws = (char*)d_ws;
    float* s    = (float*)ws;                                       // 3,200,000 B
    float* weff = (float*)(ws + 3200000);                           // 512 B
    unsigned long long* cand = (unsigned long long*)(ws + 3201024); // 256,000 B
    uint16_t* rep = (uint16_t*)(ws + 3457024);                      // 256*32768*2 = 16.8 MB

    k_y_topk_all<<<T_STEPS * NB1, 256, 0, stream>>>(X, p, cand);
    k_merge_gru<<<1, 512, 0, stream>>>(cand, X, Winit,
                                       W_Z, U_Z, B_Z, W_R, U_R, B_R, W_H, U_H, B_H,
                                       lin_w, weff);
    k_s_all<<<T_STEPS * NB3, 256, 0, stream>>>(X, weff, s);
    k_scatter_lds<<<SC_BLKS, 1024, dynLDS, stream>>>(erow, ecol, evalv, s, rep);
    k_reduce<<<T_STEPS * NB3, 256, 0, stream>>>(rep, lin_b, out);
}